// Round 10
// baseline (706.677 us; speedup 1.0000x reference)
//
#include <hip/hip_runtime.h>

// ---------------------------------------------------------------------------
// GCN fraud detector. Per layer:
//   h' = dis_row * (relu_bn_prev(X) @ W)    (bf16 MFMA GEMM, dis folded in)
//   out[d] = dis[d] * ( sum_{s in N(d)} h'[s] + h'[d] )   (bucket gather, bf16)
//   BN stats (vectorized kernel) -> scale/shift folded into NEXT consumer load.
// Head: relu(h@wc1+bc1)@wc2+bc2. GCN bias cancels through BN -> dropped.
// Graph build: 2-pass binned partition (bin = dst>>7), 4-wide edge processing.
// Agg: R8 structure (wave/node, ushort2 row loads, 16 gathers in flight).
//   R8/R9 lessons: MLP>8 free; 2B-load channel split regresses (inst count
//   doubles, XCD steering doesn't move FETCH). agg128 ~59us = line-fill floor.
// ---------------------------------------------------------------------------

typedef __attribute__((ext_vector_type(8))) short short8;
typedef __attribute__((ext_vector_type(4))) float f32x4;

#define BIN_SHIFT 7
#define BIN_NODES 128
#define CAPB 4096
#define CAP 64

__device__ __forceinline__ float b2f(unsigned short u) {
    return __uint_as_float(((unsigned)u) << 16);
}
__device__ __forceinline__ unsigned short f2bf(float f) {
    unsigned u = __float_as_uint(f);
    return (unsigned short)((u + 0x7fff + ((u >> 16) & 1)) >> 16);
}

// --- P1: partition edges into 128-node bins, packed (src<<7 | dst&127) ---
__global__ __launch_bounds__(256) void part1_kernel(const int* __restrict__ eidx,
                                                    int E, int nbins, int chunk,
                                                    int* __restrict__ bin_fill,
                                                    int* __restrict__ binned) {
    __shared__ int cntS[1024];
    __shared__ int baseS[1024];
    int tid = threadIdx.x;
    for (int b = tid; b < nbins; b += 256) cntS[b] = 0;
    __syncthreads();
    int e0 = blockIdx.x * chunk;
    int e1 = min(e0 + chunk, E);
    for (int i = e0 + tid * 4; i < e1; i += 1024) {
        int4 d4 = *(const int4*)&eidx[E + i];
        atomicAdd(&cntS[d4.x >> BIN_SHIFT], 1);
        atomicAdd(&cntS[d4.y >> BIN_SHIFT], 1);
        atomicAdd(&cntS[d4.z >> BIN_SHIFT], 1);
        atomicAdd(&cntS[d4.w >> BIN_SHIFT], 1);
    }
    __syncthreads();
    for (int b = tid; b < nbins; b += 256) {
        baseS[b] = atomicAdd(&bin_fill[b], cntS[b]);
        cntS[b] = 0;
    }
    __syncthreads();
    for (int i = e0 + tid * 4; i < e1; i += 1024) {
        int4 d4 = *(const int4*)&eidx[E + i];
        int4 s4 = *(const int4*)&eidx[i];
#pragma unroll
        for (int k = 0; k < 4; k++) {
            int d = (k == 0) ? d4.x : (k == 1) ? d4.y : (k == 2) ? d4.z : d4.w;
            int s = (k == 0) ? s4.x : (k == 1) ? s4.y : (k == 2) ? s4.z : s4.w;
            int b = d >> BIN_SHIFT;
            int p = baseS[b] + atomicAdd(&cntS[b], 1);
            if (p < CAPB)
                binned[b * CAPB + p] = (s << BIN_SHIFT) | (d & (BIN_NODES - 1));
        }
    }
}

// --- P2: block per bin; LDS slot assignment; stage writes stay L2-resident ---
__global__ __launch_bounds__(256) void part2_kernel(const int* __restrict__ bin_fill,
                                                    const int* __restrict__ binned,
                                                    int N, int* __restrict__ fill,
                                                    float* __restrict__ dis,
                                                    int* __restrict__ stage) {
    __shared__ int lfill[BIN_NODES];
    int b = blockIdx.x, tid = threadIdx.x;
    if (tid < BIN_NODES) lfill[tid] = 0;
    __syncthreads();
    int cnt = min(bin_fill[b], CAPB);
    const int* seg = binned + b * CAPB;
    for (int i = tid * 4; i < cnt; i += 1024) {
        int4 v4 = *(const int4*)&seg[i];
#pragma unroll
        for (int k = 0; k < 4; k++) {
            if (i + k >= cnt) break;
            int v = (k == 0) ? v4.x : (k == 1) ? v4.y : (k == 2) ? v4.z : v4.w;
            int dl = v & (BIN_NODES - 1);
            int p = atomicAdd(&lfill[dl], 1);
            int node = (b << BIN_SHIFT) + dl;
            if (p < CAP) stage[(node << 6) + p] = v >> BIN_SHIFT;
        }
    }
    __syncthreads();
    if (tid < BIN_NODES) {
        int node = (b << BIN_SHIFT) + tid;
        if (node < N) {
            int c = lfill[tid];
            fill[node] = c;
            dis[node] = rsqrtf((float)c + 1.0f);
        }
    }
}

// Repack all three W matrices fp32 -> bf16 B-fragment order (one launch).
// frag idx = ((n_tile*4 + q)*64 + lane)*8 + j ; k = q*32+(lane>>4)*8+j
__global__ void wfrag_kernel(const float* __restrict__ w0,
                             const float* __restrict__ w1,
                             const float* __restrict__ w2,
                             unsigned short* __restrict__ wf) {
    int tid = blockIdx.x * 256 + threadIdx.x;
    if (tid >= 40960) return;
    const float* w;
    int idx, C;
    if (tid < 16384) { w = w0; idx = tid; C = 128; }
    else if (tid < 32768) { w = w1; idx = tid - 16384; C = 128; }
    else { w = w2; idx = tid - 32768; C = 64; }
    int j = idx & 7;
    int lane = (idx >> 3) & 63;
    int q = (idx >> 9) & 3;
    int n_tile = idx >> 11;
    int k = q * 32 + (lane >> 4) * 8 + j;
    int n = n_tile * 16 + (lane & 15);
    wf[tid] = f2bf(w[k * C + n]);
}

__device__ __forceinline__ void load8(const float* p, float4& lo, float4& hi) {
    lo = *(const float4*)p;
    hi = *(const float4*)(p + 4);
}
__device__ __forceinline__ void load8(const unsigned short* p, float4& lo, float4& hi) {
    int4 q = *(const int4*)p;
    lo = make_float4(__uint_as_float((unsigned)q.x << 16),
                     __uint_as_float((unsigned)q.x & 0xffff0000u),
                     __uint_as_float((unsigned)q.y << 16),
                     __uint_as_float((unsigned)q.y & 0xffff0000u));
    hi = make_float4(__uint_as_float((unsigned)q.z << 16),
                     __uint_as_float((unsigned)q.z & 0xffff0000u),
                     __uint_as_float((unsigned)q.w << 16),
                     __uint_as_float((unsigned)q.w & 0xffff0000u));
}

// --- MFMA GEMM: out[N x C](bf16) = dis_row * (relu(xin*scale+shift) @ W) ---
template <int C, typename InT>
__global__ __launch_bounds__(256, 5) void mfma_gemm_kernel(
    const InT* __restrict__ xin, const unsigned short* __restrict__ wf,
    const float* __restrict__ scale, const float* __restrict__ shift,
    const float* __restrict__ dis, unsigned short* __restrict__ out, int N) {
    constexpr int NT = C / 16;
    constexpr int WFRAGS = NT * 4 * 64;
    __shared__ short8 ws[WFRAGS];
    int tid = threadIdx.x;
    for (int i = tid; i < WFRAGS; i += 256) ws[i] = ((const short8*)wf)[i];

    int lane = tid & 63;
    int wave = tid >> 6;
    int m0 = blockIdx.x * 64 + wave * 16;
    int r15 = lane & 15, r4 = lane >> 4;
    f32x4 acc[NT];
#pragma unroll
    for (int t = 0; t < NT; t++) acc[t] = (f32x4){0.f, 0.f, 0.f, 0.f};
    int row0 = m0 + r15;
    int row0c = min(row0, N - 1);
    __syncthreads();

#pragma unroll
    for (int q = 0; q < 4; q++) {
        int kb = q * 32 + r4 * 8;
        float4 a0l, a0h;
        load8(xin + (size_t)row0c * 128 + kb, a0l, a0h);
        if (scale) {
            float4 scl = *(const float4*)&scale[kb];
            float4 sch = *(const float4*)&scale[kb + 4];
            float4 shl = *(const float4*)&shift[kb];
            float4 shh = *(const float4*)&shift[kb + 4];
            a0l.x = fmaxf(a0l.x * scl.x + shl.x, 0.f);
            a0l.y = fmaxf(a0l.y * scl.y + shl.y, 0.f);
            a0l.z = fmaxf(a0l.z * scl.z + shl.z, 0.f);
            a0l.w = fmaxf(a0l.w * scl.w + shl.w, 0.f);
            a0h.x = fmaxf(a0h.x * sch.x + shh.x, 0.f);
            a0h.y = fmaxf(a0h.y * sch.y + shh.y, 0.f);
            a0h.z = fmaxf(a0h.z * sch.z + shh.z, 0.f);
            a0h.w = fmaxf(a0h.w * sch.w + shh.w, 0.f);
        }
        short8 a0;
        a0[0] = (short)f2bf(a0l.x); a0[1] = (short)f2bf(a0l.y);
        a0[2] = (short)f2bf(a0l.z); a0[3] = (short)f2bf(a0l.w);
        a0[4] = (short)f2bf(a0h.x); a0[5] = (short)f2bf(a0h.y);
        a0[6] = (short)f2bf(a0h.z); a0[7] = (short)f2bf(a0h.w);
#pragma unroll
        for (int nt = 0; nt < NT; nt++) {
            short8 b = ws[(nt * 4 + q) * 64 + lane];
            acc[nt] = __builtin_amdgcn_mfma_f32_16x16x32_bf16(a0, b, acc[nt], 0, 0, 0);
        }
    }
    float d0r[4];
#pragma unroll
    for (int r = 0; r < 4; r++) {
        int rowa = m0 + r4 * 4 + r;
        d0r[r] = (rowa < N) ? dis[rowa] : 0.f;
    }
#pragma unroll
    for (int nt = 0; nt < NT; nt++) {
        int col = nt * 16 + r15;
#pragma unroll
        for (int r = 0; r < 4; r++) {
            int rowa = m0 + r4 * 4 + r;
            if (rowa < N) out[(size_t)rowa * C + col] = f2bf(acc[nt][r] * d0r[r]);
        }
    }
}

// --- agg C=128: one wave per node, 4 nodes/block, 16 gathers in flight ---
__global__ __launch_bounds__(256) void agg128_kernel(
    const unsigned short* __restrict__ h, const int* __restrict__ fill,
    const int* __restrict__ stage, const float* __restrict__ dis,
    unsigned short* __restrict__ out, int N) {
    int lane = threadIdx.x & 63;
    int node = blockIdx.x * 4 + (threadIdx.x >> 6);
    if (node >= N) return;
    float dn = dis[node];
    ushort2 sv = ((const ushort2*)(h + (size_t)node * 128))[lane];
    float2 acc = make_float2(b2f(sv.x), b2f(sv.y));
    int ne = min(fill[node], CAP);
    int pk = (lane < ne) ? stage[(node << 6) + lane] : 0;
    int j = 0;
    for (; j + 16 <= ne; j += 16) {
        ushort2 a[16];
#pragma unroll
        for (int t = 0; t < 16; t++) {
            int s = __builtin_amdgcn_readlane(pk, j + t);
            a[t] = ((const ushort2*)(h + (size_t)s * 128))[lane];
        }
#pragma unroll
        for (int t = 0; t < 16; t++) { acc.x += b2f(a[t].x); acc.y += b2f(a[t].y); }
    }
    for (; j + 8 <= ne; j += 8) {
        ushort2 a[8];
#pragma unroll
        for (int t = 0; t < 8; t++) {
            int s = __builtin_amdgcn_readlane(pk, j + t);
            a[t] = ((const ushort2*)(h + (size_t)s * 128))[lane];
        }
#pragma unroll
        for (int t = 0; t < 8; t++) { acc.x += b2f(a[t].x); acc.y += b2f(a[t].y); }
    }
    for (; j + 4 <= ne; j += 4) {
        ushort2 a[4];
#pragma unroll
        for (int t = 0; t < 4; t++) {
            int s = __builtin_amdgcn_readlane(pk, j + t);
            a[t] = ((const ushort2*)(h + (size_t)s * 128))[lane];
        }
#pragma unroll
        for (int t = 0; t < 4; t++) { acc.x += b2f(a[t].x); acc.y += b2f(a[t].y); }
    }
    for (; j < ne; j++) {
        int s = __builtin_amdgcn_readlane(pk, j);
        ushort2 a = ((const ushort2*)(h + (size_t)s * 128))[lane];
        acc.x += b2f(a.x);
        acc.y += b2f(a.y);
    }
    ((ushort2*)(out + (size_t)node * 128))[lane] =
        make_ushort2(f2bf(acc.x * dn), f2bf(acc.y * dn));
}

// --- agg C=64: wave per node, half-wave even/odd edges, 8 loads in flight ---
__global__ __launch_bounds__(256) void agg64_kernel(
    const unsigned short* __restrict__ h, const int* __restrict__ fill,
    const int* __restrict__ stage, const float* __restrict__ dis,
    unsigned short* __restrict__ out, int N) {
    int lane = threadIdx.x & 63;
    int node = blockIdx.x * 4 + (threadIdx.x >> 6);
    if (node >= N) return;
    int half = lane >> 5, ch = lane & 31;
    float dn = dis[node];
    float2 acc = make_float2(0.f, 0.f);
    if (half == 0) {
        ushort2 sv = ((const ushort2*)(h + (size_t)node * 64))[ch];
        acc.x = b2f(sv.x);
        acc.y = b2f(sv.y);
    }
    int ne = min(fill[node], CAP);
    int pk = (lane < ne) ? stage[(node << 6) + lane] : 0;
    int j = 0;
    for (; j + 16 <= ne; j += 16) {
        ushort2 a[8];
#pragma unroll
        for (int t = 0; t < 8; t++) {
            int s = __shfl(pk, j + 2 * t + half);
            a[t] = ((const ushort2*)(h + (size_t)s * 64))[ch];
        }
#pragma unroll
        for (int t = 0; t < 8; t++) { acc.x += b2f(a[t].x); acc.y += b2f(a[t].y); }
    }
    for (; j + 8 <= ne; j += 8) {
        ushort2 a[4];
#pragma unroll
        for (int t = 0; t < 4; t++) {
            int s = __shfl(pk, j + 2 * t + half);
            a[t] = ((const ushort2*)(h + (size_t)s * 64))[ch];
        }
#pragma unroll
        for (int t = 0; t < 4; t++) { acc.x += b2f(a[t].x); acc.y += b2f(a[t].y); }
    }
    for (; j < ne; j += 2) {
        int jj = j + half;
        int s = __shfl(pk, jj);
        bool v = jj < ne;
        ushort2 a = ((const ushort2*)(h + (size_t)s * 64))[ch];
        acc.x += v ? b2f(a.x) : 0.f;
        acc.y += v ? b2f(a.y) : 0.f;
    }
    acc.x += __shfl_down(acc.x, 32);
    acc.y += __shfl_down(acc.y, 32);
    if (half == 0)
        ((ushort2*)(out + (size_t)node * 64))[ch] =
            make_ushort2(f2bf(acc.x * dn), f2bf(acc.y * dn));
}

// --- BN stats, vectorized: each thread covers 4 consecutive channels (8B) ---
template <int C>
__global__ __launch_bounds__(256) void stats_kernel(const unsigned short* __restrict__ h,
                                                    int N, float* __restrict__ sums) {
    constexpr int CG = C / 4;        // channel groups per row
    constexpr int RG = 256 / CG;     // row groups per block
    int t = threadIdx.x;
    int cg = t % CG;
    int rg = t / CG;
    float s[4] = {0.f, 0.f, 0.f, 0.f}, q[4] = {0.f, 0.f, 0.f, 0.f};
    for (int n = blockIdx.x * RG + rg; n < N; n += gridDim.x * RG) {
        ushort4 v = *(const ushort4*)&h[(size_t)n * C + cg * 4];
        float f0 = b2f(v.x), f1 = b2f(v.y), f2 = b2f(v.z), f3 = b2f(v.w);
        s[0] += f0; s[1] += f1; s[2] += f2; s[3] += f3;
        q[0] += f0 * f0; q[1] += f1 * f1; q[2] += f2 * f2; q[3] += f3 * f3;
    }
    __shared__ float red[RG][CG][8];
#pragma unroll
    for (int k = 0; k < 4; k++) {
        red[rg][cg][k] = s[k];
        red[rg][cg][4 + k] = q[k];
    }
    __syncthreads();
    if (rg == 0) {
#pragma unroll
        for (int w = 1; w < RG; w++)
#pragma unroll
            for (int k = 0; k < 4; k++) {
                s[k] += red[w][cg][k];
                q[k] += red[w][cg][4 + k];
            }
#pragma unroll
        for (int k = 0; k < 4; k++) {
            atomicAdd(&sums[cg * 4 + k], s[k]);
            atomicAdd(&sums[C + cg * 4 + k], q[k]);
        }
    }
}

template <int C>
__global__ void finalize_kernel(const float* __restrict__ sums,
                                const float* __restrict__ g,
                                const float* __restrict__ be, int N,
                                float* __restrict__ scale, float* __restrict__ shift) {
    int c = threadIdx.x;
    float inv_n = 1.0f / (float)N;
    float mean = sums[c] * inv_n;
    float var = sums[C + c] * inv_n - mean * mean;
    var = var > 0.f ? var : 0.f;
    float sc = g[c] * rsqrtf(var + 1e-5f);
    scale[c] = sc;
    shift[c] = be[c] - mean * sc;
}

__global__ __launch_bounds__(256) void head_kernel(
    const unsigned short* __restrict__ h, const float* __restrict__ scale,
    const float* __restrict__ shift, const float* __restrict__ wc1,
    const float* __restrict__ bc1, const float* __restrict__ wc2,
    const float* __restrict__ bc2, float* __restrict__ out, int N) {
    __shared__ float w1s[64 * 32];
    __shared__ float b1s[32], w2s[32], s2s[64], sh2[64];
    __shared__ float b2s;
    int tid = threadIdx.x;
    for (int i = tid; i < 64 * 32; i += 256) w1s[i] = wc1[i];
    if (tid < 32) { b1s[tid] = bc1[tid]; w2s[tid] = wc2[tid]; }
    if (tid < 64) { s2s[tid] = scale[tid]; sh2[tid] = shift[tid]; }
    if (tid == 0) b2s = bc2[0];
    __syncthreads();
    int n = blockIdx.x * 256 + tid;
    if (n >= N) return;
    float v[64];
#pragma unroll
    for (int k = 0; k < 64; k++) {
        float x = b2f(h[(size_t)n * 64 + k]) * s2s[k] + sh2[k];
        v[k] = x > 0.f ? x : 0.f;
    }
    float o = b2s;
#pragma unroll 2
    for (int j = 0; j < 32; j++) {
        float t = b1s[j];
#pragma unroll
        for (int k = 0; k < 64; k++) t += v[k] * w1s[k * 32 + j];
        t = t > 0.f ? t : 0.f;
        o += t * w2s[j];
    }
    out[n] = o;
}

extern "C" void kernel_launch(void* const* d_in, const int* in_sizes, int n_in,
                              void* d_out, int out_size, void* d_ws, size_t ws_size,
                              hipStream_t stream) {
    const float* x = (const float*)d_in[0];
    const int* eidx = (const int*)d_in[1];
    const float* w0 = (const float*)d_in[2];
    const float* g0 = (const float*)d_in[4];
    const float* be0 = (const float*)d_in[5];
    const float* w1 = (const float*)d_in[6];
    const float* g1 = (const float*)d_in[8];
    const float* be1 = (const float*)d_in[9];
    const float* w2 = (const float*)d_in[10];
    const float* g2 = (const float*)d_in[12];
    const float* be2 = (const float*)d_in[13];
    const float* wc1 = (const float*)d_in[14];
    const float* bc1 = (const float*)d_in[15];
    const float* wc2 = (const float*)d_in[16];
    const float* bc2 = (const float*)d_in[17];

    const int N = in_sizes[0] / 128;
    const int E = in_sizes[1] / 2;
    const int nbins = (N + BIN_NODES - 1) >> BIN_SHIFT;

    char* p = (char*)d_ws;
    auto alloc = [&](size_t bytes) {
        void* r = (void*)p;
        p += (bytes + 255) & ~(size_t)255;
        return r;
    };
    float* sums = (float*)alloc(3 * 256 * 4);
    int* bin_fill = (int*)alloc((size_t)nbins * 4);
    size_t zero_bytes = (size_t)(p - (char*)d_ws);
    int* fill = (int*)alloc((size_t)N * 4);
    int* binned = (int*)alloc((size_t)nbins * CAPB * 4);
    int* stage = (int*)alloc((size_t)N * CAP * 4);
    float* dis = (float*)alloc((size_t)N * 4);
    float* ss = (float*)alloc(3 * 256 * 4);
    unsigned short* hA = (unsigned short*)alloc((size_t)N * 128 * 2);
    unsigned short* hB = (unsigned short*)alloc((size_t)N * 128 * 2);
    unsigned short* wf = (unsigned short*)alloc(40960 * 2);
    unsigned short* wf0 = wf;
    unsigned short* wf1 = wf + 16384;
    unsigned short* wf2 = wf + 32768;

    float* sums0 = sums, *sums1 = sums + 256, *sums2 = sums + 512;
    float* sc0 = ss, *sh0 = ss + 128;
    float* sc1 = ss + 256, *sh1 = ss + 384;
    float* sc2 = ss + 512, *sh2 = ss + 640;

    hipMemsetAsync(d_ws, 0, zero_bytes, stream);

    // --- W repack (all three) + graph build ---
    wfrag_kernel<<<160, 256, 0, stream>>>(w0, w1, w2, wf);
    int p1_blocks = 256;
    int chunk = ((E + p1_blocks - 1) / p1_blocks + 3) & ~3;
    part1_kernel<<<p1_blocks, 256, 0, stream>>>(eidx, E, nbins, chunk, bin_fill, binned);
    part2_kernel<<<nbins, 256, 0, stream>>>(bin_fill, binned, N, fill, dis, stage);

    int agg_grid = (N + 3) / 4;
    int gemm_grid = (N + 63) / 64;

    // --- layer 0 ---
    mfma_gemm_kernel<128, float><<<gemm_grid, 256, 0, stream>>>(x, wf0, nullptr, nullptr,
                                                                dis, hA, N);
    agg128_kernel<<<agg_grid, 256, 0, stream>>>(hA, fill, stage, dis, hB, N);
    stats_kernel<128><<<1024, 256, 0, stream>>>(hB, N, sums0);
    finalize_kernel<128><<<1, 128, 0, stream>>>(sums0, g0, be0, N, sc0, sh0);

    // --- layer 1 ---
    mfma_gemm_kernel<128, unsigned short><<<gemm_grid, 256, 0, stream>>>(
        hB, wf1, sc0, sh0, dis, hA, N);
    agg128_kernel<<<agg_grid, 256, 0, stream>>>(hA, fill, stage, dis, hB, N);
    stats_kernel<128><<<1024, 256, 0, stream>>>(hB, N, sums1);
    finalize_kernel<128><<<1, 128, 0, stream>>>(sums1, g1, be1, N, sc1, sh1);

    // --- layer 2 (128 -> 64) ---
    mfma_gemm_kernel<64, unsigned short><<<gemm_grid, 256, 0, stream>>>(
        hB, wf2, sc1, sh1, dis, hA, N);
    agg64_kernel<<<agg_grid, 256, 0, stream>>>(hA, fill, stage, dis, hB, N);
    stats_kernel<64><<<1024, 256, 0, stream>>>(hB, N, sums2);
    finalize_kernel<64><<<1, 64, 0, stream>>>(sums2, g2, be2, N, sc2, sh2);

    // --- head ---
    head_kernel<<<(N + 255) / 256, 256, 0, stream>>>(hB, sc2, sh2, wc1, bc1, wc2,
                                                     bc2, (float*)d_out, N);
}

// Round 11
// 432.648 us; speedup vs baseline: 1.6334x; 1.6334x over previous
//
#include <hip/hip_runtime.h>

// ---------------------------------------------------------------------------
// GCN fraud detector. Per layer:
//   h' = dis_row * (relu_bn_prev(X) @ W)    (bf16 MFMA GEMM, dis folded in)
//   out[d] = dis[d] * ( sum_{s in N(d)} h'[s] + h'[d] )   (bucket gather, bf16)
//   BN stats: 2-stage tree reduction, NO atomics (R10 lesson: 1024-deep
//     same-address atomicAdd chains cost ~100us regardless of byte count).
// Head: relu(h@wc1+bc1)@wc2+bc2. GCN bias cancels through BN -> dropped.
// Graph build: 2-pass binned partition (bin = dst>>7), scalar (R10's 4-wide
//   variant regressed ~+100us).
// Agg: wave/node, ushort2 row loads, 16 gathers in flight. ~59us = line-fill
//   floor (R8: MLP>8 free; R9: 2B channel-split regresses).
// ---------------------------------------------------------------------------

typedef __attribute__((ext_vector_type(8))) short short8;
typedef __attribute__((ext_vector_type(4))) float f32x4;

#define BIN_SHIFT 7
#define BIN_NODES 128
#define CAPB 4096
#define CAP 64
#define SPARTS 1024  // stats1 grid / partial count

__device__ __forceinline__ float b2f(unsigned short u) {
    return __uint_as_float(((unsigned)u) << 16);
}
__device__ __forceinline__ unsigned short f2bf(float f) {
    unsigned u = __float_as_uint(f);
    return (unsigned short)((u + 0x7fff + ((u >> 16) & 1)) >> 16);
}

// --- P1: partition edges into 128-node bins, packed (src<<7 | dst&127) ---
__global__ __launch_bounds__(256) void part1_kernel(const int* __restrict__ eidx,
                                                    int E, int nbins, int chunk,
                                                    int* __restrict__ bin_fill,
                                                    int* __restrict__ binned) {
    __shared__ int cntS[1024];
    __shared__ int baseS[1024];
    int tid = threadIdx.x;
    for (int b = tid; b < nbins; b += 256) cntS[b] = 0;
    __syncthreads();
    int e0 = blockIdx.x * chunk;
    int e1 = min(e0 + chunk, E);
    for (int e = e0 + tid; e < e1; e += 256)
        atomicAdd(&cntS[eidx[E + e] >> BIN_SHIFT], 1);
    __syncthreads();
    for (int b = tid; b < nbins; b += 256) {
        baseS[b] = atomicAdd(&bin_fill[b], cntS[b]);
        cntS[b] = 0;
    }
    __syncthreads();
    for (int e = e0 + tid; e < e1; e += 256) {
        int d = eidx[E + e];
        int s = eidx[e];
        int b = d >> BIN_SHIFT;
        int p = baseS[b] + atomicAdd(&cntS[b], 1);
        if (p < CAPB) binned[b * CAPB + p] = (s << BIN_SHIFT) | (d & (BIN_NODES - 1));
    }
}

// --- P2: block per bin; LDS slot assignment; stage writes stay L2-resident ---
__global__ __launch_bounds__(256) void part2_kernel(const int* __restrict__ bin_fill,
                                                    const int* __restrict__ binned,
                                                    int N, int* __restrict__ fill,
                                                    float* __restrict__ dis,
                                                    int* __restrict__ stage) {
    __shared__ int lfill[BIN_NODES];
    int b = blockIdx.x, tid = threadIdx.x;
    if (tid < BIN_NODES) lfill[tid] = 0;
    __syncthreads();
    int cnt = min(bin_fill[b], CAPB);
    const int* seg = binned + b * CAPB;
    for (int i = tid; i < cnt; i += 256) {
        int v = seg[i];
        int dl = v & (BIN_NODES - 1);
        int p = atomicAdd(&lfill[dl], 1);
        int node = (b << BIN_SHIFT) + dl;
        if (p < CAP) stage[(node << 6) + p] = v >> BIN_SHIFT;
    }
    __syncthreads();
    if (tid < BIN_NODES) {
        int node = (b << BIN_SHIFT) + tid;
        if (node < N) {
            int c = lfill[tid];
            fill[node] = c;
            dis[node] = rsqrtf((float)c + 1.0f);
        }
    }
}

// Repack all three W matrices fp32 -> bf16 B-fragment order (one launch).
__global__ void wfrag_kernel(const float* __restrict__ w0,
                             const float* __restrict__ w1,
                             const float* __restrict__ w2,
                             unsigned short* __restrict__ wf) {
    int tid = blockIdx.x * 256 + threadIdx.x;
    if (tid >= 40960) return;
    const float* w;
    int idx, C;
    if (tid < 16384) { w = w0; idx = tid; C = 128; }
    else if (tid < 32768) { w = w1; idx = tid - 16384; C = 128; }
    else { w = w2; idx = tid - 32768; C = 64; }
    int j = idx & 7;
    int lane = (idx >> 3) & 63;
    int q = (idx >> 9) & 3;
    int n_tile = idx >> 11;
    int k = q * 32 + (lane >> 4) * 8 + j;
    int n = n_tile * 16 + (lane & 15);
    wf[tid] = f2bf(w[k * C + n]);
}

__device__ __forceinline__ void load8(const float* p, float4& lo, float4& hi) {
    lo = *(const float4*)p;
    hi = *(const float4*)(p + 4);
}
__device__ __forceinline__ void load8(const unsigned short* p, float4& lo, float4& hi) {
    int4 q = *(const int4*)p;
    lo = make_float4(__uint_as_float((unsigned)q.x << 16),
                     __uint_as_float((unsigned)q.x & 0xffff0000u),
                     __uint_as_float((unsigned)q.y << 16),
                     __uint_as_float((unsigned)q.y & 0xffff0000u));
    hi = make_float4(__uint_as_float((unsigned)q.z << 16),
                     __uint_as_float((unsigned)q.z & 0xffff0000u),
                     __uint_as_float((unsigned)q.w << 16),
                     __uint_as_float((unsigned)q.w & 0xffff0000u));
}

// --- MFMA GEMM: out[N x C](bf16) = dis_row * (relu(xin*scale+shift) @ W) ---
template <int C, typename InT>
__global__ __launch_bounds__(256, 5) void mfma_gemm_kernel(
    const InT* __restrict__ xin, const unsigned short* __restrict__ wf,
    const float* __restrict__ scale, const float* __restrict__ shift,
    const float* __restrict__ dis, unsigned short* __restrict__ out, int N) {
    constexpr int NT = C / 16;
    constexpr int WFRAGS = NT * 4 * 64;
    __shared__ short8 ws[WFRAGS];
    int tid = threadIdx.x;
    for (int i = tid; i < WFRAGS; i += 256) ws[i] = ((const short8*)wf)[i];

    int lane = tid & 63;
    int wave = tid >> 6;
    int m0 = blockIdx.x * 64 + wave * 16;
    int r15 = lane & 15, r4 = lane >> 4;
    f32x4 acc[NT];
#pragma unroll
    for (int t = 0; t < NT; t++) acc[t] = (f32x4){0.f, 0.f, 0.f, 0.f};
    int row0 = m0 + r15;
    int row0c = min(row0, N - 1);
    __syncthreads();

#pragma unroll
    for (int q = 0; q < 4; q++) {
        int kb = q * 32 + r4 * 8;
        float4 a0l, a0h;
        load8(xin + (size_t)row0c * 128 + kb, a0l, a0h);
        if (scale) {
            float4 scl = *(const float4*)&scale[kb];
            float4 sch = *(const float4*)&scale[kb + 4];
            float4 shl = *(const float4*)&shift[kb];
            float4 shh = *(const float4*)&shift[kb + 4];
            a0l.x = fmaxf(a0l.x * scl.x + shl.x, 0.f);
            a0l.y = fmaxf(a0l.y * scl.y + shl.y, 0.f);
            a0l.z = fmaxf(a0l.z * scl.z + shl.z, 0.f);
            a0l.w = fmaxf(a0l.w * scl.w + shl.w, 0.f);
            a0h.x = fmaxf(a0h.x * sch.x + shh.x, 0.f);
            a0h.y = fmaxf(a0h.y * sch.y + shh.y, 0.f);
            a0h.z = fmaxf(a0h.z * sch.z + shh.z, 0.f);
            a0h.w = fmaxf(a0h.w * sch.w + shh.w, 0.f);
        }
        short8 a0;
        a0[0] = (short)f2bf(a0l.x); a0[1] = (short)f2bf(a0l.y);
        a0[2] = (short)f2bf(a0l.z); a0[3] = (short)f2bf(a0l.w);
        a0[4] = (short)f2bf(a0h.x); a0[5] = (short)f2bf(a0h.y);
        a0[6] = (short)f2bf(a0h.z); a0[7] = (short)f2bf(a0h.w);
#pragma unroll
        for (int nt = 0; nt < NT; nt++) {
            short8 b = ws[(nt * 4 + q) * 64 + lane];
            acc[nt] = __builtin_amdgcn_mfma_f32_16x16x32_bf16(a0, b, acc[nt], 0, 0, 0);
        }
    }
    float d0r[4];
#pragma unroll
    for (int r = 0; r < 4; r++) {
        int rowa = m0 + r4 * 4 + r;
        d0r[r] = (rowa < N) ? dis[rowa] : 0.f;
    }
#pragma unroll
    for (int nt = 0; nt < NT; nt++) {
        int col = nt * 16 + r15;
#pragma unroll
        for (int r = 0; r < 4; r++) {
            int rowa = m0 + r4 * 4 + r;
            if (rowa < N) out[(size_t)rowa * C + col] = f2bf(acc[nt][r] * d0r[r]);
        }
    }
}

// --- agg C=128: one wave per node, 4 nodes/block, 16 gathers in flight ---
__global__ __launch_bounds__(256) void agg128_kernel(
    const unsigned short* __restrict__ h, const int* __restrict__ fill,
    const int* __restrict__ stage, const float* __restrict__ dis,
    unsigned short* __restrict__ out, int N) {
    int lane = threadIdx.x & 63;
    int node = blockIdx.x * 4 + (threadIdx.x >> 6);
    if (node >= N) return;
    float dn = dis[node];
    ushort2 sv = ((const ushort2*)(h + (size_t)node * 128))[lane];
    float2 acc = make_float2(b2f(sv.x), b2f(sv.y));
    int ne = min(fill[node], CAP);
    int pk = (lane < ne) ? stage[(node << 6) + lane] : 0;
    int j = 0;
    for (; j + 16 <= ne; j += 16) {
        ushort2 a[16];
#pragma unroll
        for (int t = 0; t < 16; t++) {
            int s = __builtin_amdgcn_readlane(pk, j + t);
            a[t] = ((const ushort2*)(h + (size_t)s * 128))[lane];
        }
#pragma unroll
        for (int t = 0; t < 16; t++) { acc.x += b2f(a[t].x); acc.y += b2f(a[t].y); }
    }
    for (; j + 8 <= ne; j += 8) {
        ushort2 a[8];
#pragma unroll
        for (int t = 0; t < 8; t++) {
            int s = __builtin_amdgcn_readlane(pk, j + t);
            a[t] = ((const ushort2*)(h + (size_t)s * 128))[lane];
        }
#pragma unroll
        for (int t = 0; t < 8; t++) { acc.x += b2f(a[t].x); acc.y += b2f(a[t].y); }
    }
    for (; j + 4 <= ne; j += 4) {
        ushort2 a[4];
#pragma unroll
        for (int t = 0; t < 4; t++) {
            int s = __builtin_amdgcn_readlane(pk, j + t);
            a[t] = ((const ushort2*)(h + (size_t)s * 128))[lane];
        }
#pragma unroll
        for (int t = 0; t < 4; t++) { acc.x += b2f(a[t].x); acc.y += b2f(a[t].y); }
    }
    for (; j < ne; j++) {
        int s = __builtin_amdgcn_readlane(pk, j);
        ushort2 a = ((const ushort2*)(h + (size_t)s * 128))[lane];
        acc.x += b2f(a.x);
        acc.y += b2f(a.y);
    }
    ((ushort2*)(out + (size_t)node * 128))[lane] =
        make_ushort2(f2bf(acc.x * dn), f2bf(acc.y * dn));
}

// --- agg C=64: wave per node, half-wave even/odd edges, 8 loads in flight ---
__global__ __launch_bounds__(256) void agg64_kernel(
    const unsigned short* __restrict__ h, const int* __restrict__ fill,
    const int* __restrict__ stage, const float* __restrict__ dis,
    unsigned short* __restrict__ out, int N) {
    int lane = threadIdx.x & 63;
    int node = blockIdx.x * 4 + (threadIdx.x >> 6);
    if (node >= N) return;
    int half = lane >> 5, ch = lane & 31;
    float dn = dis[node];
    float2 acc = make_float2(0.f, 0.f);
    if (half == 0) {
        ushort2 sv = ((const ushort2*)(h + (size_t)node * 64))[ch];
        acc.x = b2f(sv.x);
        acc.y = b2f(sv.y);
    }
    int ne = min(fill[node], CAP);
    int pk = (lane < ne) ? stage[(node << 6) + lane] : 0;
    int j = 0;
    for (; j + 16 <= ne; j += 16) {
        ushort2 a[8];
#pragma unroll
        for (int t = 0; t < 8; t++) {
            int s = __shfl(pk, j + 2 * t + half);
            a[t] = ((const ushort2*)(h + (size_t)s * 64))[ch];
        }
#pragma unroll
        for (int t = 0; t < 8; t++) { acc.x += b2f(a[t].x); acc.y += b2f(a[t].y); }
    }
    for (; j + 8 <= ne; j += 8) {
        ushort2 a[4];
#pragma unroll
        for (int t = 0; t < 4; t++) {
            int s = __shfl(pk, j + 2 * t + half);
            a[t] = ((const ushort2*)(h + (size_t)s * 64))[ch];
        }
#pragma unroll
        for (int t = 0; t < 4; t++) { acc.x += b2f(a[t].x); acc.y += b2f(a[t].y); }
    }
    for (; j < ne; j += 2) {
        int jj = j + half;
        int s = __shfl(pk, jj);
        bool v = jj < ne;
        ushort2 a = ((const ushort2*)(h + (size_t)s * 64))[ch];
        acc.x += v ? b2f(a.x) : 0.f;
        acc.y += v ? b2f(a.y) : 0.f;
    }
    acc.x += __shfl_down(acc.x, 32);
    acc.y += __shfl_down(acc.y, 32);
    if (half == 0)
        ((ushort2*)(out + (size_t)node * 64))[ch] =
            make_ushort2(f2bf(acc.x * dn), f2bf(acc.y * dn));
}

// --- BN stats stage 1: per-block partial sums, NO atomics, plain stores ---
template <int C>
__global__ __launch_bounds__(256) void stats1_kernel(const unsigned short* __restrict__ h,
                                                     int N, float* __restrict__ partials) {
    constexpr int CG = C / 4;     // 4-channel groups per row
    constexpr int RG = 256 / CG;  // rows in flight per block
    int t = threadIdx.x;
    int cg = t % CG;
    int rg = t / CG;
    float s[4] = {0.f, 0.f, 0.f, 0.f}, q[4] = {0.f, 0.f, 0.f, 0.f};
    for (int n = blockIdx.x * RG + rg; n < N; n += gridDim.x * RG) {
        ushort4 v = *(const ushort4*)&h[(size_t)n * C + cg * 4];
        float f0 = b2f(v.x), f1 = b2f(v.y), f2 = b2f(v.z), f3 = b2f(v.w);
        s[0] += f0; s[1] += f1; s[2] += f2; s[3] += f3;
        q[0] += f0 * f0; q[1] += f1 * f1; q[2] += f2 * f2; q[3] += f3 * f3;
    }
    __shared__ float red[256 * 8];
#pragma unroll
    for (int k = 0; k < 4; k++) {
        red[(rg * CG + cg) * 8 + k] = s[k];
        red[(rg * CG + cg) * 8 + 4 + k] = q[k];
    }
    __syncthreads();
    if (rg == 0) {
#pragma unroll
        for (int w = 1; w < RG; w++)
#pragma unroll
            for (int k = 0; k < 4; k++) {
                s[k] += red[(w * CG + cg) * 8 + k];
                q[k] += red[(w * CG + cg) * 8 + 4 + k];
            }
        float* pb = partials + (size_t)blockIdx.x * 2 * C;
#pragma unroll
        for (int k = 0; k < 4; k++) {
            pb[cg * 4 + k] = s[k];
            pb[C + cg * 4 + k] = q[k];
        }
    }
}

// --- BN stats stage 2 (+finalize): block per channel, tree-reduce partials ---
template <int C>
__global__ __launch_bounds__(256) void stats2_kernel(const float* __restrict__ partials,
                                                     const float* __restrict__ g,
                                                     const float* __restrict__ be, int N,
                                                     float* __restrict__ scale,
                                                     float* __restrict__ shift) {
    int c = blockIdx.x;
    int t = threadIdx.x;
    float s = 0.f, q = 0.f;
    for (int b = t; b < SPARTS; b += 256) {
        const float* pb = partials + (size_t)b * 2 * C;
        s += pb[c];
        q += pb[C + c];
    }
    __shared__ float rs[256], rq[256];
    rs[t] = s;
    rq[t] = q;
    __syncthreads();
    for (int d = 128; d > 0; d >>= 1) {
        if (t < d) {
            rs[t] += rs[t + d];
            rq[t] += rq[t + d];
        }
        __syncthreads();
    }
    if (t == 0) {
        float inv_n = 1.0f / (float)N;
        float mean = rs[0] * inv_n;
        float var = rq[0] * inv_n - mean * mean;
        var = var > 0.f ? var : 0.f;
        float sc = g[c] * rsqrtf(var + 1e-5f);
        scale[c] = sc;
        shift[c] = be[c] - mean * sc;
    }
}

__global__ __launch_bounds__(256) void head_kernel(
    const unsigned short* __restrict__ h, const float* __restrict__ scale,
    const float* __restrict__ shift, const float* __restrict__ wc1,
    const float* __restrict__ bc1, const float* __restrict__ wc2,
    const float* __restrict__ bc2, float* __restrict__ out, int N) {
    __shared__ float w1s[64 * 32];
    __shared__ float b1s[32], w2s[32], s2s[64], sh2[64];
    __shared__ float b2s;
    int tid = threadIdx.x;
    for (int i = tid; i < 64 * 32; i += 256) w1s[i] = wc1[i];
    if (tid < 32) { b1s[tid] = bc1[tid]; w2s[tid] = wc2[tid]; }
    if (tid < 64) { s2s[tid] = scale[tid]; sh2[tid] = shift[tid]; }
    if (tid == 0) b2s = bc2[0];
    __syncthreads();
    int n = blockIdx.x * 256 + tid;
    if (n >= N) return;
    float v[64];
#pragma unroll
    for (int k = 0; k < 64; k++) {
        float x = b2f(h[(size_t)n * 64 + k]) * s2s[k] + sh2[k];
        v[k] = x > 0.f ? x : 0.f;
    }
    float o = b2s;
#pragma unroll 2
    for (int j = 0; j < 32; j++) {
        float t = b1s[j];
#pragma unroll
        for (int k = 0; k < 64; k++) t += v[k] * w1s[k * 32 + j];
        t = t > 0.f ? t : 0.f;
        o += t * w2s[j];
    }
    out[n] = o;
}

extern "C" void kernel_launch(void* const* d_in, const int* in_sizes, int n_in,
                              void* d_out, int out_size, void* d_ws, size_t ws_size,
                              hipStream_t stream) {
    const float* x = (const float*)d_in[0];
    const int* eidx = (const int*)d_in[1];
    const float* w0 = (const float*)d_in[2];
    const float* g0 = (const float*)d_in[4];
    const float* be0 = (const float*)d_in[5];
    const float* w1 = (const float*)d_in[6];
    const float* g1 = (const float*)d_in[8];
    const float* be1 = (const float*)d_in[9];
    const float* w2 = (const float*)d_in[10];
    const float* g2 = (const float*)d_in[12];
    const float* be2 = (const float*)d_in[13];
    const float* wc1 = (const float*)d_in[14];
    const float* bc1 = (const float*)d_in[15];
    const float* wc2 = (const float*)d_in[16];
    const float* bc2 = (const float*)d_in[17];

    const int N = in_sizes[0] / 128;
    const int E = in_sizes[1] / 2;
    const int nbins = (N + BIN_NODES - 1) >> BIN_SHIFT;

    char* p = (char*)d_ws;
    auto alloc = [&](size_t bytes) {
        void* r = (void*)p;
        p += (bytes + 255) & ~(size_t)255;
        return r;
    };
    int* bin_fill = (int*)alloc((size_t)nbins * 4);
    size_t zero_bytes = (size_t)(p - (char*)d_ws);
    int* fill = (int*)alloc((size_t)N * 4);
    int* binned = (int*)alloc((size_t)nbins * CAPB * 4);
    int* stage = (int*)alloc((size_t)N * CAP * 4);
    float* dis = (float*)alloc((size_t)N * 4);
    float* ss = (float*)alloc(3 * 256 * 4);
    float* partials = (float*)alloc((size_t)SPARTS * 256 * 4);  // reused per layer
    unsigned short* hA = (unsigned short*)alloc((size_t)N * 128 * 2);
    unsigned short* hB = (unsigned short*)alloc((size_t)N * 128 * 2);
    unsigned short* wf = (unsigned short*)alloc(40960 * 2);
    unsigned short* wf0 = wf;
    unsigned short* wf1 = wf + 16384;
    unsigned short* wf2 = wf + 32768;

    float* sc0 = ss, *sh0 = ss + 128;
    float* sc1 = ss + 256, *sh1 = ss + 384;
    float* sc2 = ss + 512, *sh2 = ss + 640;

    hipMemsetAsync(d_ws, 0, zero_bytes, stream);

    // --- W repack (all three) + graph build ---
    wfrag_kernel<<<160, 256, 0, stream>>>(w0, w1, w2, wf);
    int p1_blocks = 256;
    int chunk = (E + p1_blocks - 1) / p1_blocks;
    part1_kernel<<<p1_blocks, 256, 0, stream>>>(eidx, E, nbins, chunk, bin_fill, binned);
    part2_kernel<<<nbins, 256, 0, stream>>>(bin_fill, binned, N, fill, dis, stage);

    int agg_grid = (N + 3) / 4;
    int gemm_grid = (N + 63) / 64;

    // --- layer 0 ---
    mfma_gemm_kernel<128, float><<<gemm_grid, 256, 0, stream>>>(x, wf0, nullptr, nullptr,
                                                                dis, hA, N);
    agg128_kernel<<<agg_grid, 256, 0, stream>>>(hA, fill, stage, dis, hB, N);
    stats1_kernel<128><<<SPARTS, 256, 0, stream>>>(hB, N, partials);
    stats2_kernel<128><<<128, 256, 0, stream>>>(partials, g0, be0, N, sc0, sh0);

    // --- layer 1 ---
    mfma_gemm_kernel<128, unsigned short><<<gemm_grid, 256, 0, stream>>>(
        hB, wf1, sc0, sh0, dis, hA, N);
    agg128_kernel<<<agg_grid, 256, 0, stream>>>(hA, fill, stage, dis, hB, N);
    stats1_kernel<128><<<SPARTS, 256, 0, stream>>>(hB, N, partials);
    stats2_kernel<128><<<128, 256, 0, stream>>>(partials, g1, be1, N, sc1, sh1);

    // --- layer 2 (128 -> 64) ---
    mfma_gemm_kernel<64, unsigned short><<<gemm_grid, 256, 0, stream>>>(
        hB, wf2, sc1, sh1, dis, hA, N);
    agg64_kernel<<<agg_grid, 256, 0, stream>>>(hA, fill, stage, dis, hB, N);
    stats1_kernel<64><<<SPARTS, 256, 0, stream>>>(hB, N, partials);
    stats2_kernel<64><<<64, 256, 0, stream>>>(partials, g2, be2, N, sc2, sh2);

    // --- head ---
    head_kernel<<<(N + 255) / 256, 256, 0, stream>>>(hB, sc2, sh2, wc1, bc1, wc2,
                                                     bc2, (float*)d_out, N);
}